// Round 1
// baseline (300.052 us; speedup 1.0000x reference)
//
#include <hip/hip_runtime.h>

// Max-Feature-Map: out[b,k,h,w] = max(x[b,2k,h,w], x[b,2k+1,h,w])
// x: (32,128,112,112) fp32, out: (32,64,112,112) fp32.
// Plane size P = 112*112 = 12544 floats (P4 = 3136 float4).
// Output plane p = b*64+k corresponds to input planes 2p and 2p+1:
//   in0_elem = out_elem + p*P   (flat float4 space: in0 = i + (i/P4)*P4)

static constexpr int P4 = (112 * 112) / 4;          // 3136 float4 per plane
static constexpr int N4_OUT = 32 * 64 * P4;         // 6,422,528 output float4

__global__ __launch_bounds__(256) void mfm_kernel(const float4* __restrict__ x,
                                                  float4* __restrict__ out) {
    int i = blockIdx.x * blockDim.x + threadIdx.x;  // output float4 index
    if (i >= N4_OUT) return;
    int p = i / P4;                 // output plane index (compiler: magic-mul)
    int in0 = i + p * P4;           // = 2p*P4 + (i % P4)
    float4 a = x[in0];
    float4 b = x[in0 + P4];
    float4 r;
    r.x = fmaxf(a.x, b.x);
    r.y = fmaxf(a.y, b.y);
    r.z = fmaxf(a.z, b.z);
    r.w = fmaxf(a.w, b.w);
    out[i] = r;
}

extern "C" void kernel_launch(void* const* d_in, const int* in_sizes, int n_in,
                              void* d_out, int out_size, void* d_ws, size_t ws_size,
                              hipStream_t stream) {
    const float4* x = (const float4*)d_in[0];
    float4* out = (float4*)d_out;
    constexpr int block = 256;
    constexpr int grid = (N4_OUT + block - 1) / block;  // 25088
    mfm_kernel<<<grid, block, 0, stream>>>(x, out);
}

// Round 3
// 287.878 us; speedup vs baseline: 1.0423x; 1.0423x over previous
//
#include <hip/hip_runtime.h>

// Max-Feature-Map: out[b,k,h,w] = max(x[b,2k,h,w], x[b,2k+1,h,w])
// x: (32,128,112,112) fp32 -> out: (32,64,112,112) fp32.
// Plane size P = 112*112 = 12544 floats (P4 = 3136 float4).
// Output plane p = b*64+k reads input planes 2p and 2p+1:
//   flat float4 space: in0 = i + (i/P4)*P4, in1 = in0 + P4.
//
// Pure streaming (308 MB total, > 256 MiB L3, zero reuse) -> non-temporal
// loads/stores (nt flag) to avoid cache pollution. HIP's float4 is a struct,
// which __builtin_nontemporal_* rejects -- use a clang ext_vector_type
// (true 16 B vector, same dwordx4 codegen).

typedef float f32x4 __attribute__((ext_vector_type(4)));

static constexpr int P4 = (112 * 112) / 4;          // 3136 f32x4 per plane
static constexpr int N4_OUT = 32 * 64 * P4;         // 6,422,528 output f32x4

__global__ __launch_bounds__(256) void mfm_kernel(const f32x4* __restrict__ x,
                                                  f32x4* __restrict__ out) {
    int i = blockIdx.x * blockDim.x + threadIdx.x;  // output f32x4 index
    int p = i / P4;                                 // output plane (magic-mul)
    int in0 = i + p * P4;                           // = 2p*P4 + (i % P4)
    f32x4 a = __builtin_nontemporal_load(&x[in0]);
    f32x4 b = __builtin_nontemporal_load(&x[in0 + P4]);
    f32x4 r;
    r.x = fmaxf(a.x, b.x);
    r.y = fmaxf(a.y, b.y);
    r.z = fmaxf(a.z, b.z);
    r.w = fmaxf(a.w, b.w);
    __builtin_nontemporal_store(r, &out[i]);
}

extern "C" void kernel_launch(void* const* d_in, const int* in_sizes, int n_in,
                              void* d_out, int out_size, void* d_ws, size_t ws_size,
                              hipStream_t stream) {
    const f32x4* x = (const f32x4*)d_in[0];
    f32x4* out = (f32x4*)d_out;
    constexpr int block = 256;
    constexpr int grid = N4_OUT / block;  // 25088 exactly (N4_OUT % 256 == 0)
    mfm_kernel<<<grid, block, 0, stream>>>(x, out);
}